// Round 11
// baseline (133.468 us; speedup 1.0000x reference)
//
#include <hip/hip_runtime.h>
#include <hip/hip_fp16.h>

#define B_    4
#define C_    192
#define N_    8192
#define K_    16
#define O_    192
#define TWOC_ 384
#define BN_   (B_ * N_)
#define NSL_  48   // 4-channel slices

typedef __attribute__((ext_vector_type(8))) _Float16 half8;
typedef __attribute__((ext_vector_type(4))) _Float16 half4v;
typedef __attribute__((ext_vector_type(4))) float floatx4;
typedef __attribute__((ext_vector_type(4))) float fvec4;
typedef __attribute__((ext_vector_type(4))) int   ivec4;
typedef __attribute__((ext_vector_type(4))) unsigned int uvec4;
typedef __attribute__((ext_vector_type(2))) unsigned int uvec2;

// ---------------- K1: prep (no LDS) ----------------
// blocks 0..6143: pack x[b, 4s..4s+4, n] fp32 -> xg[b,48,N,4] fp16
// (4 coalesced channel reads -> one 8B packed store per thread).
// blocks 6144..6161: W fp32 -> fp16.
__global__ __launch_bounds__(256) void k_prep(const float* __restrict__ x,
                                              const float* __restrict__ W,
                                              unsigned short* __restrict__ xg,
                                              unsigned short* __restrict__ Wb) {
    int bid = blockIdx.x;
    int tid = threadIdx.x;

    if (bid >= 6144) {
        int base = ((bid - 6144) * 256 + tid) * 16;
        union { unsigned short u[16]; uvec4 v[2]; } o;
#pragma unroll
        for (int q = 0; q < 16; q += 4) {
            fvec4 f = __builtin_nontemporal_load((const fvec4*)(W + base + q));
            union { _Float16 h; unsigned short s; } c;
            c.h = (_Float16)f.x; o.u[q + 0] = c.s;
            c.h = (_Float16)f.y; o.u[q + 1] = c.s;
            c.h = (_Float16)f.z; o.u[q + 2] = c.s;
            c.h = (_Float16)f.w; o.u[q + 3] = c.s;
        }
        *(uvec4*)(Wb + base)     = o.v[0];
        *(uvec4*)(Wb + base + 8) = o.v[1];
        return;
    }

    // bid = (xcd: b,nh) | slice s (48) | 256-node chunk (16)
    int xcd   = bid & 7;
    int b     = xcd >> 1;
    int nh    = xcd & 1;
    int rest  = bid >> 3;                // 0..767
    int s     = rest >> 4;               // 0..47
    int chunk = rest & 15;               // 0..15
    int n     = nh * 4096 + chunk * 256 + tid;

    const float* xb = x + ((size_t)b * C_ + s * 4) * N_ + n;
    union { _Float16 h[4]; uvec2 u; } p;
#pragma unroll
    for (int c = 0; c < 4; c++)
        p.h[c] = (_Float16)__builtin_nontemporal_load(xb + (size_t)c * N_);
    *(uvec2*)(xg + ((size_t)(b * NSL_ + s) * N_ + n) * 4) = p.u;
}

// ---------------- KG: channel-sliced LDS gather, b64 reads, coalesced feed ----------------
// 1536 blocks x 256 thr = 8 XCD-pinned (b, n-half) x 48 slices x 4 subranges.
// Stage slice (all N x 4ch, 64 KiB) -> LDS; gather 1024 nodes (4/thread,
// lane-contiguous), eidx prefetch pipelined; coalesced rt[b,48,N,4] stores.
__global__ __launch_bounds__(256) void k_gather(const unsigned short* __restrict__ xg,
                                                const int* __restrict__ eidx,
                                                unsigned short* __restrict__ rt) {
    __shared__ uvec2 lds2[N_];           // 64 KiB

    int bid  = blockIdx.x;               // 1536
    int xcd  = bid & 7;
    int b    = xcd >> 1;
    int nh   = xcd & 1;
    int rest = bid >> 3;                 // 0..191
    int s    = rest % NSL_;              // 0..47
    int sub  = rest / NSL_;              // 0..3
    int nbase = nh * 4096 + sub * 1024;
    int tid  = threadIdx.x;

    const int* e0 = eidx + (size_t)b * N_ * K_;
    const int* e1 = e0 + (size_t)BN_ * K_;

    // ---- prefetch first node's indices (lane-contiguous, coalesced) ----
    ivec4 J[4], I[4];
    {
        const int* ej = e0 + (size_t)(nbase + tid) * K_;
        const int* ei = e1 + (size_t)(nbase + tid) * K_;
#pragma unroll
        for (int q = 0; q < 4; q++) {
            J[q] = *(const ivec4*)(ej + q * 4);
            I[q] = *(const ivec4*)(ei + q * 4);
        }
    }

    // ---- stage: coalesced 16B loads, conflict-free b128 LDS writes ----
    const unsigned short* src = xg + (size_t)(b * NSL_ + s) * N_ * 4;
#pragma unroll
    for (int i = 0; i < 16; i++) {
        int idx = i * 256 + tid;         // 2-node unit
        uvec4 v = *(const uvec4*)(src + (size_t)idx * 8);
        *(uvec4*)&lds2[idx * 2] = v;
    }
    __syncthreads();

    unsigned short* rto = rt + (size_t)(b * NSL_ + s) * N_ * 4;

#pragma unroll
    for (int i = 0; i < 4; i++) {
        int n = nbase + i * 256 + tid;
        // prefetch next node's indices before consuming this node's
        ivec4 Jn[4], In[4];
        if (i < 3) {
            const int* ej = e0 + (size_t)(n + 256) * K_;
            const int* ei = e1 + (size_t)(n + 256) * K_;
#pragma unroll
            for (int q = 0; q < 4; q++) {
                Jn[q] = *(const ivec4*)(ej + q * 4);
                In[q] = *(const ivec4*)(ei + q * 4);
            }
        }
        half4v m;
#pragma unroll
        for (int q = 0; q < 4; q++)
#pragma unroll
            for (int e = 0; e < 4; e++) {
                union { uvec2 u; half4v h; } jv, iv;
                jv.u = lds2[J[q][e]];
                iv.u = lds2[I[q][e]];
                half4v d = jv.h - iv.h;
                m = (q == 0 && e == 0) ? d : __builtin_elementwise_max(m, d);
            }
        union { half4v h; uvec2 u; } o;
        o.h = m;
        *(uvec2*)(rto + (size_t)n * 4) = o.u;   // coalesced 8B/lane contiguous
#pragma unroll
        for (int q = 0; q < 4; q++) { J[q] = Jn[q]; I[q] = In[q]; }
    }
}

// ---------------- KC: 1x1 conv GEMM (fp16 MFMA), swizzled LDS y-tile ----------------
// 512 blocks x 4 waves; block = 64 nodes. Both y-halves staged from sliced
// layouts: xs from xg[b,48,N,4], rel from rt[b,48,N,4].
__global__ __launch_bounds__(256) void k_conv(const unsigned short* __restrict__ xg,
                                              const unsigned short* __restrict__ rt,
                                              const unsigned short* __restrict__ Wb,
                                              const float* __restrict__ bias,
                                              float* __restrict__ out) {
    __shared__ __align__(16) unsigned short ytile[64 * TWOC_];   // 48 KiB
    char* yb = (char*)ytile;

    int bid  = blockIdx.x;               // 512
    int xcd  = bid & 7;
    int b    = xcd >> 1;
    int slot = bid >> 3;                 // 0..63
    int n0   = ((xcd & 1) * 64 + slot) * 64;

    int tid  = threadIdx.x;
    int wave = tid >> 6;
    int lane = tid & 63;
    int m16  = lane & 15;
    int quad = lane >> 4;

    // ---- stage y = [xs | rel], both from [b,48,N,4]: 16B = 2 nodes of one slice ----
#pragma unroll
    for (int i = 0; i < 6; i++) {
        int id = i * 256 + tid;          // 0..1535
        int s  = id >> 5;                // 0..47
        int np = id & 31;                // node-pair 0..31
        int r1 = np * 2, r2 = np * 2 + 1;
        size_t goff = ((size_t)(b * NSL_ + s) * N_ + n0 + r1) * 4;
        uvec4 vx = *(const uvec4*)(xg + goff);
        uvec4 vr = *(const uvec4*)(rt + goff);
        uvec2 x1 = {vx.x, vx.y}, x2 = {vx.z, vx.w};
        uvec2 r1v = {vr.x, vr.y}, r2v = {vr.z, vr.w};
        int sw1 = (r1 & 7) << 4, sw2 = (r2 & 7) << 4;
        *(uvec2*)(yb + r1 * 768 + ((s * 8) ^ sw1))         = x1;
        *(uvec2*)(yb + r2 * 768 + ((s * 8) ^ sw2))         = x2;
        *(uvec2*)(yb + r1 * 768 + ((384 + s * 8) ^ sw1))   = r1v;
        *(uvec2*)(yb + r2 * 768 + ((384 + s * 8) ^ sw2))   = r2v;
    }
    __syncthreads();

    const unsigned short* wbase = Wb + (size_t)(wave * 48 + m16) * TWOC_ + quad * 8;

    floatx4 acc[3][4];
#pragma unroll
    for (int i = 0; i < 3; i++)
#pragma unroll
        for (int j = 0; j < 4; j++) acc[i][j] = (floatx4){0.f, 0.f, 0.f, 0.f};

#pragma unroll 2
    for (int kt = 0; kt < 12; kt++) {
        half8 wf[3], yf[4];
#pragma unroll
        for (int i = 0; i < 3; i++)
            wf[i] = *(const half8*)(wbase + (size_t)(i * 16) * TWOC_ + kt * 32);
#pragma unroll
        for (int j = 0; j < 4; j++) {
            int row = j * 16 + m16;
            yf[j] = *(const half8*)(yb + row * 768 + ((kt * 64 + quad * 16) ^ ((row & 7) << 4)));
        }
#pragma unroll
        for (int i = 0; i < 3; i++)
#pragma unroll
            for (int j = 0; j < 4; j++)
                acc[i][j] = __builtin_amdgcn_mfma_f32_16x16x32_f16(wf[i], yf[j], acc[i][j], 0, 0, 0);
    }

#pragma unroll
    for (int i = 0; i < 3; i++) {
#pragma unroll
        for (int r = 0; r < 4; r++) {
            int o = wave * 48 + i * 16 + quad * 4 + r;
            float bv = bias[o];
#pragma unroll
            for (int j = 0; j < 4; j++) {
                int n = n0 + j * 16 + m16;
                __builtin_nontemporal_store(fmaxf(acc[i][j][r] + bv, 0.f),
                                            &out[((size_t)b * O_ + o) * N_ + n]);
            }
        }
    }
}

extern "C" void kernel_launch(void* const* d_in, const int* in_sizes, int n_in,
                              void* d_out, int out_size, void* d_ws, size_t ws_size,
                              hipStream_t stream) {
    const float* x    = (const float*)d_in[0];
    const int*   eidx = (const int*)d_in[2];
    const float* W    = (const float*)d_in[3];
    const float* bias = (const float*)d_in[4];
    float*       out  = (float*)d_out;

    unsigned short* Wb = (unsigned short*)d_ws;                       // 147456 B
    unsigned short* xg = (unsigned short*)((char*)d_ws + 147456);     // 12.58 MB [b,48,N,4]
    unsigned short* rt = (unsigned short*)((char*)d_ws + 12730368);   // 12.58 MB [b,48,N,4]

    k_prep<<<dim3(6162), dim3(256), 0, stream>>>(x, W, xg, Wb);
    k_gather<<<dim3(1536), dim3(256), 0, stream>>>(xg, eidx, rt);
    k_conv<<<dim3(512), dim3(256), 0, stream>>>(xg, rt, Wb, bias, out);
}